// Round 1
// baseline (684.029 us; speedup 1.0000x reference)
//
#include <hip/hip_runtime.h>

// SSAdaptiveFusion: out = x + sigmoid(W2·tanh(W1·[x;y]+b1)+b2) * (y - x)
// per-voxel channel GEMMs via f16 MFMA; HBM-streaming-bound (~780 MB).
//
// Layout: x,y,out are [B=2][C=64][DHW=507904] fp32. Block = 256 thr (4 waves),
// tile = 128 spatial x 64 out-channels. Grid = 2*3968 = 7936.

typedef float  floatx4 __attribute__((ext_vector_type(4)));
typedef _Float16 halfx8 __attribute__((ext_vector_type(8)));
typedef _Float16 halfx4 __attribute__((ext_vector_type(4)));

#define NCH   64
#define NCH2  128
#define DHW   507904
#define NSBLK 3968      /* DHW / TS */
#define TS    128
#define LDW1  136       /* xy tile row stride in f16 (272B, 16B-aligned) */
#define LDW2  72        /* h tile row stride in f16 (144B, 16B-aligned) */

__device__ __forceinline__ float fast_tanh(float v) {
  float a = fabsf(v);
  float t = __expf(-2.0f * a);
  float m = (1.0f - t) / (1.0f + t);   // t<=1, no overflow
  return copysignf(m, v);
}
__device__ __forceinline__ float fast_sigmoid(float v) {
  return 1.0f / (1.0f + __expf(-v));
}

__global__ __launch_bounds__(256) void fusion_kernel(
    const float* __restrict__ x, const float* __restrict__ y,
    const float* __restrict__ w1, const float* __restrict__ b1,
    const float* __restrict__ w2, const float* __restrict__ b2,
    float* __restrict__ out)
{
  // xy tile, f16, [s][c] with c = 0..127 over concat(x,y)
  __shared__ _Float16 sxy[TS * LDW1];            // 34816 B
  // per-wave private h tile, [16 s][64 c]
  __shared__ _Float16 sh[4 * 16 * LDW2];         // 9216 B

  const int tid = threadIdx.x;
  const int blk = blockIdx.x;
  const int b   = blk / NSBLK;
  const int s0  = (blk - b * NSBLK) * TS;

  const float* xb = x   + (size_t)b * NCH * DHW;
  const float* yb = y   + (size_t)b * NCH * DHW;
  float*       ob = out + (size_t)b * NCH * DHW;

  // ---- stage x,y tile -> LDS f16 [s][c]; transpose 4x4 in registers ----
  {
    const int s4  = tid & 31;   // spatial quad
    const int c4b = tid >> 5;   // 0..7
#pragma unroll
    for (int it = 0; it < 4; ++it) {
      const int c4 = it * 8 + c4b;            // channel quad 0..31 (never straddles x/y)
      const int c0 = c4 * 4;
      const float* p0 = (c0 < NCH) ? (xb + (size_t)c0 * DHW)
                                   : (yb + (size_t)(c0 - NCH) * DHW);
      const float* ps = p0 + s0 + s4 * 4;
      float4 v0 = *(const float4*)(ps);
      float4 v1 = *(const float4*)(ps + (size_t)DHW);
      float4 v2 = *(const float4*)(ps + 2 * (size_t)DHW);
      float4 v3 = *(const float4*)(ps + 3 * (size_t)DHW);
      const float* f0 = (const float*)&v0;
      const float* f1 = (const float*)&v1;
      const float* f2 = (const float*)&v2;
      const float* f3 = (const float*)&v3;
#pragma unroll
      for (int i = 0; i < 4; ++i) {
        halfx4 pk;
        pk[0] = (_Float16)f0[i];
        pk[1] = (_Float16)f1[i];
        pk[2] = (_Float16)f2[i];
        pk[3] = (_Float16)f3[i];
        *(halfx4*)&sxy[(s4 * 4 + i) * LDW1 + c0] = pk;
      }
    }
  }
  __syncthreads();

  const int lane = tid & 63;
  const int w    = tid >> 6;
  const int q    = lane >> 4;
  const int r    = lane & 15;

  // ---- A fragments (weights) in registers; A[m=r][k=q*8+j] ----
  halfx8 a1f[4][4];
#pragma unroll
  for (int mt = 0; mt < 4; ++mt) {
    const float* row = w1 + (size_t)(mt * 16 + r) * NCH2;
#pragma unroll
    for (int kk = 0; kk < 4; ++kk) {
      float4 lo = *(const float4*)(row + kk * 32 + q * 8);
      float4 hi = *(const float4*)(row + kk * 32 + q * 8 + 4);
      halfx8 f;
      f[0]=(_Float16)lo.x; f[1]=(_Float16)lo.y; f[2]=(_Float16)lo.z; f[3]=(_Float16)lo.w;
      f[4]=(_Float16)hi.x; f[5]=(_Float16)hi.y; f[6]=(_Float16)hi.z; f[7]=(_Float16)hi.w;
      a1f[mt][kk] = f;
    }
  }
  halfx8 a2f[4][2];
#pragma unroll
  for (int mt = 0; mt < 4; ++mt) {
    const float* row = w2 + (size_t)(mt * 16 + r) * NCH;
#pragma unroll
    for (int kk = 0; kk < 2; ++kk) {
      float4 lo = *(const float4*)(row + kk * 32 + q * 8);
      float4 hi = *(const float4*)(row + kk * 32 + q * 8 + 4);
      halfx8 f;
      f[0]=(_Float16)lo.x; f[1]=(_Float16)lo.y; f[2]=(_Float16)lo.z; f[3]=(_Float16)lo.w;
      f[4]=(_Float16)hi.x; f[5]=(_Float16)hi.y; f[6]=(_Float16)hi.z; f[7]=(_Float16)hi.w;
      a2f[mt][kk] = f;
    }
  }
  float4 b1v[4], b2v[4];
#pragma unroll
  for (int mt = 0; mt < 4; ++mt) {
    b1v[mt] = *(const float4*)(b1 + mt * 16 + q * 4);
    b2v[mt] = *(const float4*)(b2 + mt * 16 + q * 4);
  }

  _Float16* shw = sh + w * (16 * LDW2);

  // ---- each wave: 2 s-tiles, all 64 out channels ----
#pragma unroll
  for (int sti = 0; sti < 2; ++sti) {
    const int st   = w * 2 + sti;       // s-tile 0..7
    const int srow = st * 16 + r;       // local spatial row

    // GEMM1: H = tanh(W1 * XY + b1)
    floatx4 acc[4];
#pragma unroll
    for (int mt = 0; mt < 4; ++mt) acc[mt] = (floatx4){0.f, 0.f, 0.f, 0.f};
#pragma unroll
    for (int kk = 0; kk < 4; ++kk) {
      halfx8 bf = *(const halfx8*)&sxy[srow * LDW1 + kk * 32 + q * 8];
#pragma unroll
      for (int mt = 0; mt < 4; ++mt)
        acc[mt] = __builtin_amdgcn_mfma_f32_16x16x32_f16(a1f[mt][kk], bf, acc[mt], 0, 0, 0);
    }

    // epilogue 1: tanh, write h to per-wave LDS region [r][c]
    __asm__ __volatile__("" ::: "memory");
#pragma unroll
    for (int mt = 0; mt < 4; ++mt) {
      halfx4 hp;
#pragma unroll
      for (int e = 0; e < 4; ++e)
        hp[e] = (_Float16)fast_tanh(acc[mt][e] + ((const float*)&b1v[mt])[e]);
      *(halfx4*)&shw[r * LDW2 + mt * 16 + q * 4] = hp;
    }
    __asm__ __volatile__("s_waitcnt lgkmcnt(0)" ::: "memory");

    // GEMM2: G = sigmoid(W2 * H + b2)
    floatx4 acc2[4];
#pragma unroll
    for (int mt = 0; mt < 4; ++mt) acc2[mt] = (floatx4){0.f, 0.f, 0.f, 0.f};
#pragma unroll
    for (int kk = 0; kk < 2; ++kk) {
      halfx8 bf2 = *(const halfx8*)&shw[r * LDW2 + kk * 32 + q * 8];
#pragma unroll
      for (int mt = 0; mt < 4; ++mt)
        acc2[mt] = __builtin_amdgcn_mfma_f32_16x16x32_f16(a2f[mt][kk], bf2, acc2[mt], 0, 0, 0);
    }

    // epilogue 2: sigmoid, gated blend (x,y re-read from LDS), store fp32
#pragma unroll
    for (int mt = 0; mt < 4; ++mt) {
      halfx4 xv = *(const halfx4*)&sxy[srow * LDW1 + mt * 16 + q * 4];
      halfx4 yv = *(const halfx4*)&sxy[srow * LDW1 + NCH + mt * 16 + q * 4];
#pragma unroll
      for (int e = 0; e < 4; ++e) {
        float g  = fast_sigmoid(acc2[mt][e] + ((const float*)&b2v[mt])[e]);
        float xf = (float)xv[e];
        float yf = (float)yv[e];
        int ch   = mt * 16 + q * 4 + e;
        ob[(size_t)ch * DHW + s0 + srow] = xf + g * (yf - xf);
      }
    }
    __asm__ __volatile__("" ::: "memory");  // WAR fence before next sti rewrites shw
  }
}

extern "C" void kernel_launch(void* const* d_in, const int* in_sizes, int n_in,
                              void* d_out, int out_size, void* d_ws, size_t ws_size,
                              hipStream_t stream) {
  const float* x  = (const float*)d_in[0];
  const float* y  = (const float*)d_in[1];
  const float* w1 = (const float*)d_in[2];
  const float* b1 = (const float*)d_in[3];
  const float* w2 = (const float*)d_in[4];
  const float* b2 = (const float*)d_in[5];
  float* out = (float*)d_out;

  fusion_kernel<<<dim3(2 * NSBLK), dim3(256), 0, stream>>>(x, y, w1, b1, w2, b2, out);
}